// Round 5
// baseline (157.467 us; speedup 1.0000x reference)
//
#include <hip/hip_runtime.h>

// WeightedKappaLoss: kappa = 1 - (N * sum(W*conf)) / sum(W_ij * ht_i * hp_j)
// conf = 6x6 confusion histogram of (y_true, argmax(y_pred_row)).
// softmax is monotone -> argmax on raw logits. All counts exact integers;
// final ratio in double -> absmax == 0 vs reference (verified R0/R2/R4).
//
// R5: R4's LDS bounce + per-chunk fence was NEUTRAL (155.6 vs R0 153.3):
// the fence serializes each wave's iteration chain (same-buffer reuse kills
// inter-iteration pipelining), cancelling the request-rate win. This version
// maximizes MLP instead:
//   - direct stride-48 float4 loads (correct in R0/R2; each 64B line fetched
//     once from L2/HBM, the 3x instruction overlap is an L1 hit)
//   - each thread owns 4 INDEPENDENT pairs; all 16 loads (12 dwordx4 +
//     4 dwordx2) are issued before any compute (static-index arrays + full
//     unroll -> registers, rule-#20 safe) -> deep per-wave MLP, no fences,
//     no cross-lane exchange, nothing for the scheduler to stall on
//   - per-wave LDS histograms (no inter-wave atomic serialization)
//   - race-free per-block 144 B partial store; two-kernel reduction
//     (R2 measured the fused last-block fan-in at ~+95 us: 2048 same-address
//     device atomics + per-block __threadfence — never again)
// Fills (2 x 384 MB poison @ ~85% peak = ~112 us) are harness-owned floor.

#define NC 6
#define NBINS 36
#define BLOCK 256
#define WPB (BLOCK / 64)            // 4 waves per block
#define PAIRS_PER_WAVE 256          // 4 groups of 64 lanes
#define GRID 2048                   // 2048*256*4 pairs = 2,097,152 >= 2e6
#define SEGS 16
#define FIN_THREADS (NBINS * SEGS)  // 576 = 9 waves

__global__ __launch_bounds__(BLOCK) void kappa_count(
    const float4* __restrict__ yp4, const int2* __restrict__ yt2,
    const float* __restrict__ yp, const int* __restrict__ yt,
    unsigned int* __restrict__ gconf, int npairs, int N) {
    __shared__ unsigned int sconf[WPB][NBINS];   // per-wave histograms
    const int tid = threadIdx.x;
    const int w = tid >> 6;
    const int L = tid & 63;
    if (tid < WPB * NBINS) ((unsigned int*)sconf)[tid] = 0u;
    __syncthreads();

    unsigned int* my = sconf[w];
    const long long gstride = (long long)GRID * WPB * PAIRS_PER_WAVE;

    for (long long base = ((long long)blockIdx.x * WPB + w) * PAIRS_PER_WAVE;
         base < npairs; base += gstride) {
        if (base + PAIRS_PER_WAVE <= npairs) {
            // Fast path: 4 independent pair-groups, ALL loads issued first.
            float4 A[4], B[4], D[4];
            int2 T[4];
            #pragma unroll
            for (int k = 0; k < 4; ++k) {
                const long long i = base + (long long)k * 64 + L;
                A[k] = yp4[3 * i];
                B[k] = yp4[3 * i + 1];
                D[k] = yp4[3 * i + 2];
                T[k] = yt2[i];
            }
            #pragma unroll
            for (int k = 0; k < 4; ++k) {
                // row 0: A.x A.y A.z A.w B.x B.y (strict > = first max = argmax)
                float m = A[k].x; int p = 0;
                if (A[k].y > m) { m = A[k].y; p = 1; }
                if (A[k].z > m) { m = A[k].z; p = 2; }
                if (A[k].w > m) { m = A[k].w; p = 3; }
                if (B[k].x > m) { m = B[k].x; p = 4; }
                if (B[k].y > m) { m = B[k].y; p = 5; }
                atomicAdd(&my[T[k].x * NC + p], 1u);
                // row 1: B.z B.w D.x D.y D.z D.w
                m = B[k].z; p = 0;
                if (B[k].w > m) { m = B[k].w; p = 1; }
                if (D[k].x > m) { m = D[k].x; p = 2; }
                if (D[k].y > m) { m = D[k].y; p = 3; }
                if (D[k].z > m) { m = D[k].z; p = 4; }
                if (D[k].w > m) { m = D[k].w; p = 5; }
                atomicAdd(&my[T[k].y * NC + p], 1u);
            }
        } else {
            // Tail path: per-pair guard.
            #pragma unroll
            for (int k = 0; k < 4; ++k) {
                const long long i = base + (long long)k * 64 + L;
                if (i < npairs) {
                    const float4 a = yp4[3 * i];
                    const float4 b = yp4[3 * i + 1];
                    const float4 d = yp4[3 * i + 2];
                    const int2 t = yt2[i];
                    float m = a.x; int p = 0;
                    if (a.y > m) { m = a.y; p = 1; }
                    if (a.z > m) { m = a.z; p = 2; }
                    if (a.w > m) { m = a.w; p = 3; }
                    if (b.x > m) { m = b.x; p = 4; }
                    if (b.y > m) { m = b.y; p = 5; }
                    atomicAdd(&my[t.x * NC + p], 1u);
                    m = b.z; p = 0;
                    if (b.w > m) { m = b.w; p = 1; }
                    if (d.x > m) { m = d.x; p = 2; }
                    if (d.y > m) { m = d.y; p = 3; }
                    if (d.z > m) { m = d.z; p = 4; }
                    if (d.w > m) { m = d.w; p = 5; }
                    atomicAdd(&my[t.y * NC + p], 1u);
                }
            }
        }
    }

    // odd-N tail row (N=4e6 is even; kept for generality)
    if ((N & 1) && blockIdx.x == 0 && tid == 0) {
        const int r = N - 1;
        float m = yp[r * NC]; int p = 0;
        #pragma unroll
        for (int j = 1; j < NC; ++j) {
            const float v = yp[r * NC + j];
            if (v > m) { m = v; p = j; }
        }
        atomicAdd(&my[yt[r] * NC + p], 1u);
    }

    __syncthreads();
    // Race-free per-block writedown: merge 4 wave histograms, one coalesced
    // 144 B store per block. No global atomics, no fences, no prior memset.
    if (tid < NBINS) {
        unsigned int s = 0;
        #pragma unroll
        for (int k = 0; k < WPB; ++k) s += sconf[k][tid];
        gconf[blockIdx.x * NBINS + tid] = s;
    }
}

__global__ void kappa_final_kernel(const unsigned int* __restrict__ gconf,
                                   float* __restrict__ out, long long N) {
    // Stage 2a: 576 threads, each sums 128 of the 2048 partials for one bin.
    // Independent scalar loads, 9 waves -> MLP + TLP hide latency.
    __shared__ unsigned int part[SEGS][NBINS];
    __shared__ unsigned int conf_s[NBINS];
    const int tid = threadIdx.x;
    if (tid < FIN_THREADS) {
        const int bin = tid % NBINS;
        const int seg = tid / NBINS;
        unsigned int s = 0;
        const int b0 = seg * (GRID / SEGS);
        #pragma unroll 8
        for (int b = b0; b < b0 + GRID / SEGS; ++b) s += gconf[b * NBINS + bin];
        part[seg][bin] = s;
    }
    __syncthreads();
    if (tid < NBINS) {
        unsigned int tot = 0;
        #pragma unroll
        for (int s2 = 0; s2 < SEGS; ++s2) tot += part[s2][tid];
        conf_s[tid] = tot;   // per-bin total <= N=4e6, exact in u32
    }
    __syncthreads();
    if (tid == 0) {
        long long conf[NBINS], ht[NC], hp[NC];
        #pragma unroll
        for (int i = 0; i < NC; ++i) { ht[i] = 0; hp[i] = 0; }
        #pragma unroll
        for (int k = 0; k < NBINS; ++k) conf[k] = (long long)conf_s[k];

        long long num = 0;
        #pragma unroll
        for (int i = 0; i < NC; ++i)
            #pragma unroll
            for (int j = 0; j < NC; ++j) {
                const long long w = (long long)(i - j) * (i - j);
                num += w * conf[i * NC + j];
                ht[i] += conf[i * NC + j];
                hp[j] += conf[i * NC + j];
            }
        long long den = 0;
        #pragma unroll
        for (int i = 0; i < NC; ++i)
            #pragma unroll
            for (int j = 0; j < NC; ++j)
                den += (long long)(i - j) * (i - j) * ht[i] * hp[j];

        out[0] = (float)(1.0 - ((double)num * (double)N) / (double)den);
    }
}

extern "C" void kernel_launch(void* const* d_in, const int* in_sizes, int n_in,
                              void* d_out, int out_size, void* d_ws, size_t ws_size,
                              hipStream_t stream) {
    const float* yp = (const float*)d_in[0];
    const int* yt = (const int*)d_in[1];   // int32 on device (verified: absmax=0)
    const int N = in_sizes[1];
    unsigned int* gconf = (unsigned int*)d_ws;  // GRID*NBINS uints = 288 KB

    const int npairs = N / 2;
    kappa_count<<<GRID, BLOCK, 0, stream>>>(
        (const float4*)yp, (const int2*)yt, yp, yt, gconf, npairs, N);
    kappa_final_kernel<<<1, FIN_THREADS, 0, stream>>>(gconf, (float*)d_out,
                                                      (long long)N);
}

// Round 6
// 148.814 us; speedup vs baseline: 1.0581x; 1.0581x over previous
//
#include <hip/hip_runtime.h>

// WeightedKappaLoss: kappa = 1 - (N * sum(W*conf)) / sum(W_ij * ht_i * hp_j)
// conf = 6x6 confusion histogram of (y_true, argmax(y_pred_row)).
// softmax is monotone -> argmax on raw logits. All counts exact integers;
// final ratio in double -> absmax == 0 vs reference (verified R0/R2/R4/R5).
//
// R6: three structurally distinct count kernels (R0 direct stride-48, R4
// LDS-staged coalesced, R5 4-deep register-MLP) all land at 153-157 us ->
// count (~30 us for 112 MB = 3.7 TB/s) is NOT latency- or request-rate-
// bound. Last cache-level hypothesis: the harness's 384 MB poison fills
// dirty the whole 256 MB L3 between iterations; our read allocations then
// fight fill-dirtied lines (R2 loop: 55 MB of 112 MB "served by L3" with
// zero time benefit). This version reads both streams NON-TEMPORALLY
// (nt policy: no allocate / evict-first) via __builtin_nontemporal_load.
// If neutral, code-shape levers are exhausted (external pin / roofline).
// Structure = R0's proven-simplest: 1024 blocks x 256, direct stride-48
// float4 loads, per-wave LDS histograms, race-free per-block 144 B partial
// store, separate small reduction kernel (R2 proved fused last-block
// fan-in costs ~95 us: 2048 same-address device atomics + fences).

#define NC 6
#define NBINS 36
#define BLOCK 256
#define WPB (BLOCK / 64)            // 4 waves per block
#define GRID 1024                   // 4 blocks/CU, 16 waves/CU (R0 config)
#define SEGS 16
#define FIN_THREADS (NBINS * SEGS)  // 576 = 9 waves

typedef float f4 __attribute__((ext_vector_type(4)));

__global__ __launch_bounds__(BLOCK) void kappa_count(
    const f4* __restrict__ yp4, const unsigned long long* __restrict__ yt2,
    const float* __restrict__ yp, const int* __restrict__ yt,
    unsigned int* __restrict__ gconf, int npairs, int N) {
    __shared__ unsigned int sconf[WPB][NBINS];   // per-wave histograms
    const int tid = threadIdx.x;
    const int w = tid >> 6;
    if (tid < WPB * NBINS) ((unsigned int*)sconf)[tid] = 0u;
    __syncthreads();

    unsigned int* my = sconf[w];
    const int stride = GRID * BLOCK;

    for (int i = blockIdx.x * BLOCK + tid; i < npairs; i += stride) {
        // Non-temporal: read-through, no L3 allocation, no dirty-line fights.
        const f4 a = __builtin_nontemporal_load(&yp4[3 * i]);
        const f4 b = __builtin_nontemporal_load(&yp4[3 * i + 1]);
        const f4 d = __builtin_nontemporal_load(&yp4[3 * i + 2]);
        const unsigned long long tt = __builtin_nontemporal_load(&yt2[i]);
        const int t0 = (int)(tt & 0xffffffffull);
        const int t1 = (int)(tt >> 32);

        // row 0: a0 a1 a2 a3 b0 b1 (strict > keeps first max = jnp.argmax)
        float m = a.x; int p = 0;
        if (a.y > m) { m = a.y; p = 1; }
        if (a.z > m) { m = a.z; p = 2; }
        if (a.w > m) { m = a.w; p = 3; }
        if (b.x > m) { m = b.x; p = 4; }
        if (b.y > m) { m = b.y; p = 5; }
        atomicAdd(&my[t0 * NC + p], 1u);

        // row 1: b2 b3 d0 d1 d2 d3
        m = b.z; p = 0;
        if (b.w > m) { m = b.w; p = 1; }
        if (d.x > m) { m = d.x; p = 2; }
        if (d.y > m) { m = d.y; p = 3; }
        if (d.z > m) { m = d.z; p = 4; }
        if (d.w > m) { m = d.w; p = 5; }
        atomicAdd(&my[t1 * NC + p], 1u);
    }

    // odd-N tail row (N=4e6 is even; kept for generality)
    if ((N & 1) && blockIdx.x == 0 && tid == 0) {
        const int r = N - 1;
        float m = yp[r * NC]; int p = 0;
        #pragma unroll
        for (int j = 1; j < NC; ++j) {
            const float v = yp[r * NC + j];
            if (v > m) { m = v; p = j; }
        }
        atomicAdd(&my[yt[r] * NC + p], 1u);
    }

    __syncthreads();
    // Race-free per-block writedown: merge 4 wave histograms, one coalesced
    // 144 B store per block. No global atomics, no fences, no prior memset.
    if (tid < NBINS) {
        unsigned int s = 0;
        #pragma unroll
        for (int k = 0; k < WPB; ++k) s += sconf[k][tid];
        gconf[blockIdx.x * NBINS + tid] = s;
    }
}

__global__ void kappa_final_kernel(const unsigned int* __restrict__ gconf,
                                   float* __restrict__ out, long long N) {
    // 576 threads, each sums 64 of the 1024 partials for one bin (9 waves,
    // independent unrolled loads -> latency hidden).
    __shared__ unsigned int part[SEGS][NBINS];
    __shared__ unsigned int conf_s[NBINS];
    const int tid = threadIdx.x;
    if (tid < FIN_THREADS) {
        const int bin = tid % NBINS;
        const int seg = tid / NBINS;
        unsigned int s = 0;
        const int b0 = seg * (GRID / SEGS);
        #pragma unroll 8
        for (int b = b0; b < b0 + GRID / SEGS; ++b) s += gconf[b * NBINS + bin];
        part[seg][bin] = s;
    }
    __syncthreads();
    if (tid < NBINS) {
        unsigned int tot = 0;
        #pragma unroll
        for (int s2 = 0; s2 < SEGS; ++s2) tot += part[s2][tid];
        conf_s[tid] = tot;   // per-bin total <= N=4e6, exact in u32
    }
    __syncthreads();
    if (tid == 0) {
        long long conf[NBINS], ht[NC], hp[NC];
        #pragma unroll
        for (int i = 0; i < NC; ++i) { ht[i] = 0; hp[i] = 0; }
        #pragma unroll
        for (int k = 0; k < NBINS; ++k) conf[k] = (long long)conf_s[k];

        long long num = 0;
        #pragma unroll
        for (int i = 0; i < NC; ++i)
            #pragma unroll
            for (int j = 0; j < NC; ++j) {
                const long long w = (long long)(i - j) * (i - j);
                num += w * conf[i * NC + j];
                ht[i] += conf[i * NC + j];
                hp[j] += conf[i * NC + j];
            }
        long long den = 0;
        #pragma unroll
        for (int i = 0; i < NC; ++i)
            #pragma unroll
            for (int j = 0; j < NC; ++j)
                den += (long long)(i - j) * (i - j) * ht[i] * hp[j];

        out[0] = (float)(1.0 - ((double)num * (double)N) / (double)den);
    }
}

extern "C" void kernel_launch(void* const* d_in, const int* in_sizes, int n_in,
                              void* d_out, int out_size, void* d_ws, size_t ws_size,
                              hipStream_t stream) {
    const float* yp = (const float*)d_in[0];
    const int* yt = (const int*)d_in[1];   // int32 on device (verified: absmax=0)
    const int N = in_sizes[1];
    unsigned int* gconf = (unsigned int*)d_ws;  // GRID*NBINS uints = 144 KB

    const int npairs = N / 2;
    kappa_count<<<GRID, BLOCK, 0, stream>>>(
        (const f4*)yp, (const unsigned long long*)yt, yp, yt, gconf, npairs, N);
    kappa_final_kernel<<<1, FIN_THREADS, 0, stream>>>(gconf, (float*)d_out,
                                                      (long long)N);
}